// Round 1
// baseline (881.328 us; speedup 1.0000x reference)
//
#include <hip/hip_runtime.h>
#include <math.h>

#define NNODES 38400
#define KNBR 8

// ---------------- GEMM: Y[N, 2*Co] = X[N,Ci] @ [tw; pw]^T ----------------
// 64x64 tile, BK=16, 256 threads, 4x4 microtile per thread.
__global__ __launch_bounds__(256) void gemm_cat(
    const float* __restrict__ X, int Ci,
    const float* __restrict__ Wt, const float* __restrict__ Wp, int Co,
    float* __restrict__ Y)
{
    const int Cout2 = 2 * Co;
    const int bm = blockIdx.x, bn = blockIdx.y;
    const int tid = threadIdx.x;
    __shared__ float Xs[16][68];
    __shared__ float Ws[16][68];
    const int tx = tid & 15, ty = tid >> 4;
    float acc[4][4] = {};
    const int row0 = bm * 64;
    const int col0 = bn * 64;

    for (int k0 = 0; k0 < Ci; k0 += 16) {
#pragma unroll
        for (int i = 0; i < 4; ++i) {
            int idx = tid + i * 256;     // 0..1023
            int kk = idx >> 6, m = idx & 63;
            int k = k0 + kk;
            Xs[kk][m] = (k < Ci) ? X[(size_t)(row0 + m) * Ci + k] : 0.f;
        }
#pragma unroll
        for (int i = 0; i < 4; ++i) {
            int idx = tid + i * 256;
            int kk = idx >> 6, j = idx & 63;
            int k = k0 + kk;
            int jj = col0 + j;
            float w = 0.f;
            if (k < Ci && jj < Cout2)
                w = (jj < Co) ? Wt[(size_t)jj * Ci + k]
                              : Wp[(size_t)(jj - Co) * Ci + k];
            Ws[kk][j] = w;
        }
        __syncthreads();
#pragma unroll
        for (int kk = 0; kk < 16; ++kk) {
            float4 a = *reinterpret_cast<const float4*>(&Xs[kk][ty * 4]);
            float4 b = *reinterpret_cast<const float4*>(&Ws[kk][tx * 4]);
            float av[4] = {a.x, a.y, a.z, a.w};
            float bv[4] = {b.x, b.y, b.z, b.w};
#pragma unroll
            for (int i = 0; i < 4; ++i)
#pragma unroll
                for (int j = 0; j < 4; ++j)
                    acc[i][j] += av[i] * bv[j];
        }
        __syncthreads();
    }
#pragma unroll
    for (int i = 0; i < 4; ++i) {
        int r = row0 + ty * 4 + i;
#pragma unroll
        for (int j = 0; j < 4; ++j) {
            int c = col0 + tx * 4 + j;
            if (c < Cout2) Y[(size_t)r * Cout2 + c] = acc[i][j];
        }
    }
}

// -------- EdgeConv epilogue: h[n,d] = max_k Yt[nbr]-Yt[n]+tb + Yp[n]+pb ----
template <bool TANH>
__global__ void edge_epi(const float* __restrict__ Y, int Co,
                         const int* __restrict__ nbr,
                         const float* __restrict__ tb,
                         const float* __restrict__ pb,
                         float* __restrict__ H)
{
    const int n = blockIdx.x;
    const int ld = 2 * Co;
    int j[KNBR];
#pragma unroll
    for (int k = 0; k < KNBR; ++k) j[k] = nbr[n * KNBR + k];
    const float* Yn = Y + (size_t)n * ld;
    for (int d = threadIdx.x; d < Co; d += blockDim.x) {
        float m = -INFINITY;
#pragma unroll
        for (int k = 0; k < KNBR; ++k)
            m = fmaxf(m, Y[(size_t)j[k] * ld + d]);
        float v = m - Yn[d] + tb[d] + Yn[Co + d] + pb[d];
        H[(size_t)n * Co + d] = TANH ? tanhf(v) : v;
    }
}

// -------- Layer-3 epilogue with per-node channel max into g[n] ------------
__global__ __launch_bounds__(256) void edge_epi3(
    const float* __restrict__ Y, int Dc,
    const int* __restrict__ nbr,
    const float* __restrict__ tb,
    const float* __restrict__ pb,
    float* __restrict__ g, int first)
{
    const int n = blockIdx.x;
    const int ld = 2 * Dc;
    int j[KNBR];
#pragma unroll
    for (int k = 0; k < KNBR; ++k) j[k] = nbr[n * KNBR + k];
    const float* Yn = Y + (size_t)n * ld;
    float mx = -INFINITY;
    for (int d = threadIdx.x; d < Dc; d += blockDim.x) {
        float m = -INFINITY;
#pragma unroll
        for (int k = 0; k < KNBR; ++k)
            m = fmaxf(m, Y[(size_t)j[k] * ld + d]);
        float v = m - Yn[d] + tb[d] + Yn[Dc + d] + pb[d];
        mx = fmaxf(mx, v);
    }
    __shared__ float red[256];
    red[threadIdx.x] = mx;
    __syncthreads();
    for (int s = 128; s > 0; s >>= 1) {
        if (threadIdx.x < s)
            red[threadIdx.x] = fmaxf(red[threadIdx.x], red[threadIdx.x + s]);
        __syncthreads();
    }
    if (threadIdx.x == 0) {
        float v = red[0];
        g[n] = first ? v : fmaxf(g[n], v);
    }
}

// ---------------- FC head: one block per graph ----------------------------
__global__ __launch_bounds__(256) void fc_head(
    const float* __restrict__ g,  // [64, 600]
    const float* __restrict__ fc1w, const float* __restrict__ fc1b,
    const float* __restrict__ fc2w, const float* __restrict__ fc2b,
    const float* __restrict__ fc3w, const float* __restrict__ fc3b,
    const float* __restrict__ fc4w, const float* __restrict__ fc4b,
    const float* __restrict__ fow,  const float* __restrict__ fob,
    float* __restrict__ out)       // [64, 9]
{
    __shared__ float a[600];
    __shared__ float b[300];
    const int bidx = blockIdx.x;
    const int t = threadIdx.x;
    for (int i = t; i < 600; i += 256) a[i] = g[bidx * 600 + i];
    __syncthreads();
    for (int o = t; o < 300; o += 256) {
        float s = fc1b[o];
        for (int c = 0; c < 600; ++c) s += a[c] * fc1w[o * 600 + c];
        b[o] = tanhf(s);
    }
    __syncthreads();
    for (int o = t; o < 300; o += 256) {
        float s = fc2b[o];
        for (int c = 0; c < 300; ++c) s += b[c] * fc2w[o * 300 + c];
        a[o] = tanhf(s);   // a no longer needed as input
    }
    __syncthreads();
    for (int o = t; o < 100; o += 256) {
        float s = fc3b[o];
        for (int c = 0; c < 300; ++c) s += a[c] * fc3w[o * 300 + c];
        b[o] = tanhf(s);
    }
    __syncthreads();
    for (int o = t; o < 50; o += 256) {
        float s = fc4b[o];
        for (int c = 0; c < 100; ++c) s += b[c] * fc4w[o * 100 + c];
        a[o] = tanhf(s);
    }
    __syncthreads();
    for (int o = t; o < 9; o += 256) {
        float s = fob[o];
        for (int c = 0; c < 50; ++c) s += a[c] * fow[o * 50 + c];
        out[bidx * 9 + o] = fminf(fmaxf(s, -2.f), 2.f);
    }
}

extern "C" void kernel_launch(void* const* d_in, const int* in_sizes, int n_in,
                              void* d_out, int out_size, void* d_ws, size_t ws_size,
                              hipStream_t stream)
{
    const float* inputs = (const float*)d_in[0];
    const int*   nbr    = (const int*)d_in[1];
    const float* t1w = (const float*)d_in[2];  const float* t1b = (const float*)d_in[3];
    const float* p1w = (const float*)d_in[4];  const float* p1b = (const float*)d_in[5];
    const float* t2w = (const float*)d_in[6];  const float* t2b = (const float*)d_in[7];
    const float* p2w = (const float*)d_in[8];  const float* p2b = (const float*)d_in[9];
    const float* t3w = (const float*)d_in[10]; const float* t3b = (const float*)d_in[11];
    const float* p3w = (const float*)d_in[12]; const float* p3b = (const float*)d_in[13];
    const float* fc1w = (const float*)d_in[14]; const float* fc1b = (const float*)d_in[15];
    const float* fc2w = (const float*)d_in[16]; const float* fc2b = (const float*)d_in[17];
    const float* fc3w = (const float*)d_in[18]; const float* fc3b = (const float*)d_in[19];
    const float* fc4w = (const float*)d_in[20]; const float* fc4b = (const float*)d_in[21];
    const float* fow  = (const float*)d_in[22]; const float* fob  = (const float*)d_in[23];
    float* out = (float*)d_out;

    const int N = NNODES;
    char* ws = (char*)d_ws;
    size_t off = 0;
    float* h1 = (float*)(ws + off); off += (size_t)N * 100 * 4;
    float* h2 = (float*)(ws + off); off += (size_t)N * 200 * 4;
    float* g  = (float*)(ws + off); off += (size_t)N * 4;
    off = (off + 255) & ~(size_t)255;
    float* Y  = (float*)(ws + off);
    size_t ybudget = (ws_size > off) ? (ws_size - off) : 0;

    // Layer-3 channel chunk size (Y chunk needs N*2*Dc*4 bytes)
    int Dc = (int)(ybudget / ((size_t)N * 8));
    if (Dc > 600) Dc = 600;
    if (Dc < 1) Dc = 1;

    // ---- EdgeConv 1: Ci=50, Co=100 ----
    {
        dim3 grid(N / 64, (200 + 63) / 64);
        gemm_cat<<<grid, 256, 0, stream>>>(inputs, 50, t1w, p1w, 100, Y);
        edge_epi<true><<<N, 128, 0, stream>>>(Y, 100, nbr, t1b, p1b, h1);
    }
    // ---- EdgeConv 2: Ci=100, Co=200 ----
    {
        dim3 grid(N / 64, (400 + 63) / 64);
        gemm_cat<<<grid, 256, 0, stream>>>(h1, 100, t2w, p2w, 200, Y);
        edge_epi<true><<<N, 256, 0, stream>>>(Y, 200, nbr, t2b, p2b, h2);
    }
    // ---- EdgeConv 3: Ci=200, Co=600 (chunked over output channels) ----
    for (int d0 = 0; d0 < 600; d0 += Dc) {
        int D = (600 - d0 < Dc) ? (600 - d0) : Dc;
        dim3 grid(N / 64, (2 * D + 63) / 64);
        gemm_cat<<<grid, 256, 0, stream>>>(h2, 200, t3w + (size_t)d0 * 200,
                                           p3w + (size_t)d0 * 200, D, Y);
        edge_epi3<<<N, 256, 0, stream>>>(Y, D, nbr, t3b + d0, p3b + d0, g,
                                         d0 == 0 ? 1 : 0);
    }
    // ---- FC head ----
    fc_head<<<64, 256, 0, stream>>>(g, fc1w, fc1b, fc2w, fc2b, fc3w, fc3b,
                                    fc4w, fc4b, fow, fob, out);
}

// Round 2
// 379.184 us; speedup vs baseline: 2.3243x; 2.3243x over previous
//
#include <hip/hip_runtime.h>
#include <math.h>

#define NNODES 38400
#define KNBR 8

typedef __attribute__((ext_vector_type(8))) short bf16x8;
typedef __attribute__((ext_vector_type(4))) float f32x4;

// Round-to-nearest-even split of fp32 into hi+lo bf16 (bit patterns).
static __device__ inline void split_bf16(float x, short& hi, short& lo) {
    unsigned u = __float_as_uint(x);
    unsigned r = (u + 0x7FFFu + ((u >> 16) & 1u)) & 0xFFFF0000u;
    hi = (short)(r >> 16);
    float rem = x - __uint_as_float(r);
    unsigned u2 = __float_as_uint(rem);
    unsigned r2 = (u2 + 0x7FFFu + ((u2 >> 16) & 1u));
    lo = (short)(r2 >> 16);
}

// ---- MFMA GEMM: Y[M, 2*Co] = X[M,Ci] @ [Wt; Wp]^T, split-bf16 (3 MFMA) ----
// 128x128 tile, BK=32, 256 threads = 4 waves (2x2), 64x64 per wave.
__global__ __launch_bounds__(256) void gemm_mfma_split(
    const float* __restrict__ X, int Ci,
    const float* __restrict__ Wt, const float* __restrict__ Wp, int Co,
    float* __restrict__ Y)
{
    const int Cout2 = 2 * Co;
    const int row0 = blockIdx.x * 128;
    const int col0 = blockIdx.y * 128;
    const int tid = threadIdx.x;
    const int lane = tid & 63;
    const int wid = tid >> 6;
    const int wm = wid >> 1, wn = wid & 1;

    __shared__ short Ah[128][40];
    __shared__ short Al[128][40];
    __shared__ short Bh[128][40];
    __shared__ short Bl[128][40];

    f32x4 acc[4][4] = {};

    const int lr = tid >> 1;          // staging row 0..127
    const int lk = (tid & 1) * 16;    // staging k offset 0/16

    for (int k0 = 0; k0 < Ci; k0 += 32) {
        // ---- stage A tile (fp32 -> hi/lo bf16) ----
        {
            const size_t base = (size_t)(row0 + lr) * Ci + k0 + lk;
            if (((Ci & 3) == 0) && (k0 + lk + 15 < Ci)) {
#pragma unroll
                for (int i = 0; i < 16; i += 4) {
                    float4 v = *reinterpret_cast<const float4*>(X + base + i);
                    float vv[4] = {v.x, v.y, v.z, v.w};
#pragma unroll
                    for (int j = 0; j < 4; ++j) {
                        short h, l;
                        split_bf16(vv[j], h, l);
                        Ah[lr][lk + i + j] = h;
                        Al[lr][lk + i + j] = l;
                    }
                }
            } else {
#pragma unroll
                for (int i = 0; i < 16; ++i) {
                    int k = k0 + lk + i;
                    float x = (k < Ci) ? X[base + i] : 0.f;
                    short h, l;
                    split_bf16(x, h, l);
                    Ah[lr][lk + i] = h;
                    Al[lr][lk + i] = l;
                }
            }
        }
        // ---- stage B tile ([Wt;Wp] rows -> hi/lo bf16) ----
        {
            const int col = col0 + lr;
            const float* wrow = nullptr;
            if (col < Cout2)
                wrow = (col < Co) ? (Wt + (size_t)col * Ci)
                                  : (Wp + (size_t)(col - Co) * Ci);
            if (wrow && ((Ci & 3) == 0) && (k0 + lk + 15 < Ci)) {
#pragma unroll
                for (int i = 0; i < 16; i += 4) {
                    float4 v = *reinterpret_cast<const float4*>(wrow + k0 + lk + i);
                    float vv[4] = {v.x, v.y, v.z, v.w};
#pragma unroll
                    for (int j = 0; j < 4; ++j) {
                        short h, l;
                        split_bf16(vv[j], h, l);
                        Bh[lr][lk + i + j] = h;
                        Bl[lr][lk + i + j] = l;
                    }
                }
            } else {
#pragma unroll
                for (int i = 0; i < 16; ++i) {
                    int k = k0 + lk + i;
                    float x = (wrow && k < Ci) ? wrow[k] : 0.f;
                    short h, l;
                    split_bf16(x, h, l);
                    Bh[lr][lk + i] = h;
                    Bl[lr][lk + i] = l;
                }
            }
        }
        __syncthreads();

        // ---- fragments + MFMA ----
        const int fr = lane & 15;
        const int kb = (lane >> 4) * 8;
        bf16x8 ah[4], al[4], bh[4], bl[4];
#pragma unroll
        for (int f = 0; f < 4; ++f) {
            int ar = wm * 64 + f * 16 + fr;
            ah[f] = *reinterpret_cast<const bf16x8*>(&Ah[ar][kb]);
            al[f] = *reinterpret_cast<const bf16x8*>(&Al[ar][kb]);
            int bc = wn * 64 + f * 16 + fr;
            bh[f] = *reinterpret_cast<const bf16x8*>(&Bh[bc][kb]);
            bl[f] = *reinterpret_cast<const bf16x8*>(&Bl[bc][kb]);
        }
#pragma unroll
        for (int fm = 0; fm < 4; ++fm)
#pragma unroll
            for (int fn = 0; fn < 4; ++fn) {
                acc[fm][fn] = __builtin_amdgcn_mfma_f32_16x16x32_bf16(
                    ah[fm], bh[fn], acc[fm][fn], 0, 0, 0);
                acc[fm][fn] = __builtin_amdgcn_mfma_f32_16x16x32_bf16(
                    ah[fm], bl[fn], acc[fm][fn], 0, 0, 0);
                acc[fm][fn] = __builtin_amdgcn_mfma_f32_16x16x32_bf16(
                    al[fm], bh[fn], acc[fm][fn], 0, 0, 0);
            }
        __syncthreads();
    }

    // ---- store C (C/D layout: col=lane&15, row=(lane>>4)*4+reg) ----
#pragma unroll
    for (int fm = 0; fm < 4; ++fm)
#pragma unroll
        for (int fn = 0; fn < 4; ++fn) {
            int col = col0 + wn * 64 + fn * 16 + (lane & 15);
            if (col >= Cout2) continue;
#pragma unroll
            for (int r = 0; r < 4; ++r) {
                int row = row0 + wm * 64 + fm * 16 + (lane >> 4) * 4 + r;
                Y[(size_t)row * Cout2 + col] = acc[fm][fn][r];
            }
        }
}

// -------- EdgeConv epilogue: h[n,d] = max_k Yt[nbr]-Yt[n]+tb + Yp[n]+pb ----
template <bool TANH>
__global__ void edge_epi(const float* __restrict__ Y, int Co,
                         const int* __restrict__ nbr,
                         const float* __restrict__ tb,
                         const float* __restrict__ pb,
                         float* __restrict__ H)
{
    const int n = blockIdx.x;
    const int ld = 2 * Co;
    int j[KNBR];
#pragma unroll
    for (int k = 0; k < KNBR; ++k) j[k] = nbr[n * KNBR + k];
    const float* Yn = Y + (size_t)n * ld;
    for (int d = threadIdx.x; d < Co; d += blockDim.x) {
        float m = -INFINITY;
#pragma unroll
        for (int k = 0; k < KNBR; ++k)
            m = fmaxf(m, Y[(size_t)j[k] * ld + d]);
        float v = m - Yn[d] + tb[d] + Yn[Co + d] + pb[d];
        H[(size_t)n * Co + d] = TANH ? tanhf(v) : v;
    }
}

// -------- Layer-3 epilogue with per-node channel max into g[n] ------------
__global__ __launch_bounds__(256) void edge_epi3(
    const float* __restrict__ Y, int Dc,
    const int* __restrict__ nbr,
    const float* __restrict__ tb,
    const float* __restrict__ pb,
    float* __restrict__ g, int first)
{
    const int n = blockIdx.x;
    const int ld = 2 * Dc;
    int j[KNBR];
#pragma unroll
    for (int k = 0; k < KNBR; ++k) j[k] = nbr[n * KNBR + k];
    const float* Yn = Y + (size_t)n * ld;
    float mx = -INFINITY;
    for (int d = threadIdx.x; d < Dc; d += blockDim.x) {
        float m = -INFINITY;
#pragma unroll
        for (int k = 0; k < KNBR; ++k)
            m = fmaxf(m, Y[(size_t)j[k] * ld + d]);
        float v = m - Yn[d] + tb[d] + Yn[Dc + d] + pb[d];
        mx = fmaxf(mx, v);
    }
    __shared__ float red[256];
    red[threadIdx.x] = mx;
    __syncthreads();
    for (int s = 128; s > 0; s >>= 1) {
        if (threadIdx.x < s)
            red[threadIdx.x] = fmaxf(red[threadIdx.x], red[threadIdx.x + s]);
        __syncthreads();
    }
    if (threadIdx.x == 0) {
        float v = red[0];
        g[n] = first ? v : fmaxf(g[n], v);
    }
}

// ---------------- FC head: one block per graph ----------------------------
__global__ __launch_bounds__(256) void fc_head(
    const float* __restrict__ g,  // [64, 600]
    const float* __restrict__ fc1w, const float* __restrict__ fc1b,
    const float* __restrict__ fc2w, const float* __restrict__ fc2b,
    const float* __restrict__ fc3w, const float* __restrict__ fc3b,
    const float* __restrict__ fc4w, const float* __restrict__ fc4b,
    const float* __restrict__ fow,  const float* __restrict__ fob,
    float* __restrict__ out)       // [64, 9]
{
    __shared__ float a[600];
    __shared__ float b[300];
    const int bidx = blockIdx.x;
    const int t = threadIdx.x;
    for (int i = t; i < 600; i += 256) a[i] = g[bidx * 600 + i];
    __syncthreads();
    for (int o = t; o < 300; o += 256) {
        float s = fc1b[o];
        for (int c = 0; c < 600; ++c) s += a[c] * fc1w[o * 600 + c];
        b[o] = tanhf(s);
    }
    __syncthreads();
    for (int o = t; o < 300; o += 256) {
        float s = fc2b[o];
        for (int c = 0; c < 300; ++c) s += b[c] * fc2w[o * 300 + c];
        a[o] = tanhf(s);
    }
    __syncthreads();
    for (int o = t; o < 100; o += 256) {
        float s = fc3b[o];
        for (int c = 0; c < 300; ++c) s += a[c] * fc3w[o * 300 + c];
        b[o] = tanhf(s);
    }
    __syncthreads();
    for (int o = t; o < 50; o += 256) {
        float s = fc4b[o];
        for (int c = 0; c < 100; ++c) s += b[c] * fc4w[o * 100 + c];
        a[o] = tanhf(s);
    }
    __syncthreads();
    for (int o = t; o < 9; o += 256) {
        float s = fob[o];
        for (int c = 0; c < 50; ++c) s += a[c] * fow[o * 50 + c];
        out[bidx * 9 + o] = fminf(fmaxf(s, -2.f), 2.f);
    }
}

extern "C" void kernel_launch(void* const* d_in, const int* in_sizes, int n_in,
                              void* d_out, int out_size, void* d_ws, size_t ws_size,
                              hipStream_t stream)
{
    const float* inputs = (const float*)d_in[0];
    const int*   nbr    = (const int*)d_in[1];
    const float* t1w = (const float*)d_in[2];  const float* t1b = (const float*)d_in[3];
    const float* p1w = (const float*)d_in[4];  const float* p1b = (const float*)d_in[5];
    const float* t2w = (const float*)d_in[6];  const float* t2b = (const float*)d_in[7];
    const float* p2w = (const float*)d_in[8];  const float* p2b = (const float*)d_in[9];
    const float* t3w = (const float*)d_in[10]; const float* t3b = (const float*)d_in[11];
    const float* p3w = (const float*)d_in[12]; const float* p3b = (const float*)d_in[13];
    const float* fc1w = (const float*)d_in[14]; const float* fc1b = (const float*)d_in[15];
    const float* fc2w = (const float*)d_in[16]; const float* fc2b = (const float*)d_in[17];
    const float* fc3w = (const float*)d_in[18]; const float* fc3b = (const float*)d_in[19];
    const float* fc4w = (const float*)d_in[20]; const float* fc4b = (const float*)d_in[21];
    const float* fow  = (const float*)d_in[22]; const float* fob  = (const float*)d_in[23];
    float* out = (float*)d_out;

    const int N = NNODES;
    char* ws = (char*)d_ws;
    size_t off = 0;
    float* h1 = (float*)(ws + off); off += (size_t)N * 100 * 4;
    float* h2 = (float*)(ws + off); off += (size_t)N * 200 * 4;
    float* g  = (float*)(ws + off); off += (size_t)N * 4;
    off = (off + 255) & ~(size_t)255;
    float* Y  = (float*)(ws + off);
    size_t ybudget = (ws_size > off) ? (ws_size - off) : 0;

    // Layer-3 channel chunk size (Y chunk needs N*2*Dc*4 bytes)
    int Dc = (int)(ybudget / ((size_t)N * 8));
    if (Dc > 600) Dc = 600;
    if (Dc < 1) Dc = 1;

    // ---- EdgeConv 1: Ci=50, Co=100 ----
    {
        dim3 grid(N / 128, (200 + 127) / 128);
        gemm_mfma_split<<<grid, 256, 0, stream>>>(inputs, 50, t1w, p1w, 100, Y);
        edge_epi<true><<<N, 128, 0, stream>>>(Y, 100, nbr, t1b, p1b, h1);
    }
    // ---- EdgeConv 2: Ci=100, Co=200 ----
    {
        dim3 grid(N / 128, (400 + 127) / 128);
        gemm_mfma_split<<<grid, 256, 0, stream>>>(h1, 100, t2w, p2w, 200, Y);
        edge_epi<true><<<N, 256, 0, stream>>>(Y, 200, nbr, t2b, p2b, h2);
    }
    // ---- EdgeConv 3: Ci=200, Co=600 (chunked over output channels) ----
    for (int d0 = 0; d0 < 600; d0 += Dc) {
        int D = (600 - d0 < Dc) ? (600 - d0) : Dc;
        dim3 grid(N / 128, (2 * D + 127) / 128);
        gemm_mfma_split<<<grid, 256, 0, stream>>>(h2, 200, t3w + (size_t)d0 * 200,
                                                  p3w + (size_t)d0 * 200, D, Y);
        edge_epi3<<<N, 256, 0, stream>>>(Y, D, nbr, t3b + d0, p3b + d0, g,
                                         d0 == 0 ? 1 : 0);
    }
    // ---- FC head ----
    fc_head<<<64, 256, 0, stream>>>(g, fc1w, fc1b, fc2w, fc2b, fc3w, fc3b,
                                    fc4w, fc4b, fow, fob, out);
}